// Round 6
// baseline (956.221 us; speedup 1.0000x reference)
//
#include <hip/hip_runtime.h>

// NearestNeighborTokenizer: ids = (min_c ||x - c||^2 <= 900) ? argmin_c : -1
// x: [8192, 512] fp32, codes: [16384, 512] fp32, out: [8192] int32
//
// fp16x3 MFMA GEMM: x,c scaled by 16, split into fp16 hi+lo planes,
// pre-swizzled in global memory into MFMA fragment order. dot =
// (hh + hl + lh)/256 in one fp32 acc. score = ||c||^2 - 2*dot.
//
// R6: LDS-FREE K-loop. R2-R5 all pinned at ~54% MfmaUtil: any LDS-staged
// structure forces a vmcnt-drain + barrier per K-step (the compiler must
// order ds_read vs global_load_lds). Fragments are already contiguous in
// global memory (pre-swizzle), so load them straight to VGPRs and MFMA —
// no barriers, no LDS, per-load precise vmcnt, compiler free to pipeline.
// Redundant fragment reads (2x A, 4x B across waves) hit L1/L2; chunk<->XCD
// mapping keeps each XCD's 4MB B-set resident in its own L2.

#define NTOK   8192
#define NCODES 16384
#define DDIM   512
#define NCHUNK 8
#define CHUNK  2048
#define DIST_THR 900.0f

typedef unsigned short u16;
typedef _Float16 half8 __attribute__((ext_vector_type(8)));
typedef float    f32x4 __attribute__((ext_vector_type(4)));

// ---------------- kernel 1: merged prep -------------------------------------
// blocks [0,2048): convert+swizzle x -> xh/xl
// blocks [2048,6144): convert+swizzle codes -> ch/cl
// blocks [6144,10240): c2[c] = ||codes[c]||^2 (one wave per code)
//
// Swizzle: linear index c (8 halfs each):
//   r=c&15, q=(c>>4)&3, g=(c>>6)&7, kit=(c>>9)&15, tile=c>>13
//   row = tile*128 + g*16 + r ; k = kit*32 + q*8
// Each (tile,kit) is a contiguous 8KB block; within it, group g (16 rows) is
// 1KB with lane L holding 16B at [row=g*16+(L&15), k=kit*32+(L>>4)*8..+7] —
// exactly the 16x16x32 MFMA A/B fragment a wave loads with one dwordx4.
__device__ __forceinline__ void conv_body(const float* __restrict__ src,
                                          u16* __restrict__ dh,
                                          u16* __restrict__ dl, int c) {
    int r = c & 15, q = (c >> 4) & 3, g = (c >> 6) & 7, kit = (c >> 9) & 15;
    int tile = c >> 13;
    int row = tile * 128 + g * 16 + r;
    int k = kit * 32 + q * 8;
    const float* p = src + (size_t)row * DDIM + k;
    float4 v0 = *(const float4*)p;
    float4 v1 = *(const float4*)(p + 4);
    float vv[8] = {v0.x, v0.y, v0.z, v0.w, v1.x, v1.y, v1.z, v1.w};
    u16 hs[8], ls[8];
    #pragma unroll
    for (int j = 0; j < 8; ++j) {
        float sv = vv[j] * 16.0f;              // scale 16: keeps lo out of denorms
        _Float16 h = (_Float16)sv;
        float hf = (float)h;
        _Float16 l = (_Float16)(sv - hf);
        union { _Float16 f; u16 u; } uh, ul;
        uh.f = h; ul.f = l;
        hs[j] = uh.u; ls[j] = ul.u;
    }
    uint4 H, L;
    H.x = hs[0] | ((unsigned)hs[1] << 16); H.y = hs[2] | ((unsigned)hs[3] << 16);
    H.z = hs[4] | ((unsigned)hs[5] << 16); H.w = hs[6] | ((unsigned)hs[7] << 16);
    L.x = ls[0] | ((unsigned)ls[1] << 16); L.y = ls[2] | ((unsigned)ls[3] << 16);
    L.z = ls[4] | ((unsigned)ls[5] << 16); L.w = ls[6] | ((unsigned)ls[7] << 16);
    *(uint4*)(dh + (size_t)c * 8) = H;
    *(uint4*)(dl + (size_t)c * 8) = L;
}

__global__ __launch_bounds__(256) void nn_prep(const float* __restrict__ x,
                                               const float* __restrict__ codes,
                                               u16* __restrict__ xh, u16* __restrict__ xl,
                                               u16* __restrict__ ch, u16* __restrict__ cl,
                                               float* __restrict__ c2) {
    int b = blockIdx.x;
    if (b < 2048) {
        conv_body(x, xh, xl, b * 256 + threadIdx.x);
    } else if (b < 6144) {
        conv_body(codes, ch, cl, (b - 2048) * 256 + threadIdx.x);
    } else {
        int w = threadIdx.x >> 6;
        int lane = threadIdx.x & 63;
        int c = (b - 6144) * 4 + w;
        const float* p = codes + (size_t)c * DDIM + lane * 8;
        float4 v0 = *(const float4*)p;
        float4 v1 = *(const float4*)(p + 4);
        float s = v0.x*v0.x + v0.y*v0.y + v0.z*v0.z + v0.w*v0.w
                + v1.x*v1.x + v1.y*v1.y + v1.z*v1.z + v1.w*v1.w;
        #pragma unroll
        for (int off = 32; off > 0; off >>= 1) s += __shfl_down(s, off);
        if (lane == 0) c2[c] = s;
    }
}

// ---------------- kernel 2: LDS-free fp16x3 MFMA GEMM + fused argmin --------
// grid = 32 mtiles * 8 chunks, blockIdx.x = mtile*8 + chunk (chunk == XCD id:
// each XCD's 32 co-resident blocks share one 4MB B-set = its L2).
// Block: 512 threads = 8 waves; wm=wave&3 (64-row quarter of 256),
// wn=wave>>2 (128-col half of the 256-col nt-tile). Wave tile 64x128.
__global__ __launch_bounds__(512, 2) void nn_gemm(const u16* __restrict__ xh,
                                                  const u16* __restrict__ xl,
                                                  const u16* __restrict__ chh,
                                                  const u16* __restrict__ cll,
                                                  const float* __restrict__ c2,
                                                  float* __restrict__ pmin,
                                                  int* __restrict__ pid) {
    __shared__ __align__(16) char red[4096];
    const int tid = threadIdx.x;
    const int lane = tid & 63;
    const int wave = tid >> 6;          // 0..7
    const int wm = wave & 3;            // 64-row quarter
    const int wn = wave >> 2;           // 128-col half
    const int mtile = blockIdx.x >> 3;  // 0..31
    const int chunk = blockIdx.x & 7;   // 0..7
    const int m0 = mtile * 256;

    // A fragment base: 128-row tile (mtile*2 + wm/2), group base (wm&1)*4.
    // frag(i,kit) = base + kit*8192 + i*1024  (bytes)
    size_t aoff = ((size_t)(mtile * 2 + (wm >> 1)) * 16) * 8192
                + (size_t)((wm & 1) * 4) * 1024 + (size_t)lane * 16;
    const char* Ahb = (const char*)xh + aoff;
    const char* Alb = (const char*)xl + aoff;

    float mv[16];
    int   mi[16];
    #pragma unroll
    for (int s = 0; s < 16; ++s) { mv[s] = 3.4e38f; mi[s] = 0; }

    #pragma unroll 1
    for (int nt = 0; nt < 8; ++nt) {
        // B fragment base: 128-col tile (chunk*16 + nt*2 + wn).
        size_t boff = ((size_t)((chunk * 16 + nt * 2 + wn) * 16)) * 8192
                    + (size_t)lane * 16;
        const char* Bhb = (const char*)chh + boff;
        const char* Blb = (const char*)cll + boff;

        f32x4 acc[4][8];
        #pragma unroll
        for (int i = 0; i < 4; ++i)
            #pragma unroll
            for (int j = 0; j < 8; ++j) acc[i][j] = (f32x4)0.0f;

        #pragma unroll
        for (int kit = 0; kit < 16; ++kit) {
            half8 ah[4], al[4], bh[8], bl[8];
            #pragma unroll
            for (int i = 0; i < 4; ++i) {
                ah[i] = *(const half8*)(Ahb + kit * 8192 + i * 1024);
                al[i] = *(const half8*)(Alb + kit * 8192 + i * 1024);
            }
            #pragma unroll
            for (int j = 0; j < 8; ++j) {
                bh[j] = *(const half8*)(Bhb + kit * 8192 + j * 1024);
                bl[j] = *(const half8*)(Blb + kit * 8192 + j * 1024);
            }
            #pragma unroll
            for (int j = 0; j < 8; ++j)
                #pragma unroll
                for (int i = 0; i < 4; ++i) {
                    acc[i][j] = __builtin_amdgcn_mfma_f32_16x16x32_f16(ah[i], bh[j], acc[i][j], 0, 0, 0);
                    acc[i][j] = __builtin_amdgcn_mfma_f32_16x16x32_f16(ah[i], bl[j], acc[i][j], 0, 0, 0);
                    acc[i][j] = __builtin_amdgcn_mfma_f32_16x16x32_f16(al[i], bh[j], acc[i][j], 0, 0, 0);
                }
        }

        // epilogue: score = ||c||^2 - acc/128 (acc = 256 * x.c; -2/256).
        // candidates arrive in increasing code id -> '<' keeps first.
        #pragma unroll
        for (int j = 0; j < 8; ++j) {
            int ncol = nt * 256 + wn * 128 + j * 16 + (lane & 15);
            int gid = chunk * CHUNK + ncol;
            float cv = c2[gid];
            #pragma unroll
            for (int i = 0; i < 4; ++i)
                #pragma unroll
                for (int r = 0; r < 4; ++r) {
                    float s = fmaf(acc[i][j][r], -0.0078125f, cv);
                    int slot = i * 4 + r;
                    if (s < mv[slot]) { mv[slot] = s; mi[slot] = gid; }
                }
        }
    }

    // shuffle pre-reduce across the 16 col-owner lanes (xor 1,2,4,8 stay
    // within the quad; lane>>4 = row quad is preserved).
    #pragma unroll
    for (int off = 1; off < 16; off <<= 1) {
        #pragma unroll
        for (int s = 0; s < 16; ++s) {
            float ov = __shfl_xor(mv[s], off);
            int   oi = __shfl_xor(mi[s], off);
            if (ov < mv[s] || (ov == mv[s] && oi < mi[s])) { mv[s] = ov; mi[s] = oi; }
        }
    }
    // 2 contributors per row (wn=0,1)
    if ((lane & 15) == 0) {
        #pragma unroll
        for (int i = 0; i < 4; ++i)
            #pragma unroll
            for (int r = 0; r < 4; ++r) {
                int row = wm * 64 + i * 16 + (lane >> 4) * 4 + r;
                int2 e;
                e.x = __float_as_int(mv[i * 4 + r]);
                e.y = mi[i * 4 + r];
                *(int2*)(red + (wn * 256 + row) * 8) = e;
            }
    }
    __syncthreads();
    if (tid < 256) {
        int2 e0 = *(const int2*)(red + tid * 8);
        int2 e1 = *(const int2*)(red + (256 + tid) * 8);
        float v0 = __int_as_float(e0.x), v1 = __int_as_float(e1.x);
        float bv = v0; int bi = e0.y;
        if (v1 < bv || (v1 == bv && e1.y < bi)) { bv = v1; bi = e1.y; }
        pmin[(size_t)(m0 + tid) * NCHUNK + chunk] = bv;
        pid [(size_t)(m0 + tid) * NCHUNK + chunk] = bi;
    }
}

// ---------------- kernel 3: finalize (one wave per token) -------------------
__global__ __launch_bounds__(256) void nn_fin(const float* __restrict__ x,
                                              const float* __restrict__ pmin,
                                              const int* __restrict__ pid,
                                              int* __restrict__ out) {
    int w = threadIdx.x >> 6;
    int lane = threadIdx.x & 63;
    int t = blockIdx.x * 4 + w;
    const float* p = x + (size_t)t * DDIM + lane * 8;
    float4 v0 = *(const float4*)p;
    float4 v1 = *(const float4*)(p + 4);
    float s = v0.x*v0.x + v0.y*v0.y + v0.z*v0.z + v0.w*v0.w
            + v1.x*v1.x + v1.y*v1.y + v1.z*v1.z + v1.w*v1.w;
    #pragma unroll
    for (int off = 32; off > 0; off >>= 1) s += __shfl_down(s, off);
    if (lane == 0) {
        const float* pm = pmin + (size_t)t * NCHUNK;
        const int*   pi = pid  + (size_t)t * NCHUNK;
        float bv = pm[0]; int bi = pi[0];
        #pragma unroll
        for (int c = 1; c < NCHUNK; ++c) {
            float v = pm[c]; int id = pi[c];
            if (v < bv || (v == bv && id < bi)) { bv = v; bi = id; }
        }
        float mind = s + bv;   // ||x||^2 + min(||c||^2 - 2 x.c)
        out[t] = (mind <= DIST_THR) ? bi : -1;
    }
}

extern "C" void kernel_launch(void* const* d_in, const int* in_sizes, int n_in,
                              void* d_out, int out_size, void* d_ws, size_t ws_size,
                              hipStream_t stream) {
    const float* x     = (const float*)d_in[0];
    const float* codes = (const float*)d_in[1];
    int* out = (int*)d_out;

    // workspace layout (bytes):
    //  xh 8MB | xl 8MB | ch 16MB | cl 16MB | c2 64KB | pmin 256KB | pid 256KB
    char* ws = (char*)d_ws;
    u16*   xh   = (u16*)(ws);
    u16*   xl   = (u16*)(ws + 8388608);
    u16*   chh  = (u16*)(ws + 16777216);
    u16*   cll  = (u16*)(ws + 33554432);
    float* c2   = (float*)(ws + 50331648);
    float* pmin = (float*)(ws + 50397184);
    int*   pid  = (int*)  (ws + 50659328);

    nn_prep<<<10240, 256, 0, stream>>>(x, codes, xh, xl, chh, cll, c2);
    nn_gemm<<<32 * NCHUNK, 512, 0, stream>>>(xh, xl, chh, cll, c2, pmin, pid);
    nn_fin<<<NTOK / 4, 256, 0, stream>>>(x, pmin, pid, out);
}

// Round 7
// 418.890 us; speedup vs baseline: 2.2827x; 2.2827x over previous
//
#include <hip/hip_runtime.h>

// NearestNeighborTokenizer: ids = (min_c ||x - c||^2 <= 900) ? argmin_c : -1
// x: [8192, 512] fp32, codes: [16384, 512] fp32, out: [8192] int32
//
// fp16x3 MFMA GEMM: x,c scaled by 16, split into fp16 hi+lo planes,
// pre-swizzled in global memory into MFMA fragment order. dot =
// (hh + hl + lh)/256 in one fp32 acc. score = ||c||^2 - 2*dot.
//
// R7: fix the structural barrier drain by ISSUE DISTANCE, not asm waits.
// Loop body order: sync -> ds_read frags (buf it&1) -> sched_barrier ->
// stage it+1 (buf (it+1)&1) -> MFMA. The pre-barrier vmcnt(0) drain that
// killed R2-R5 now finds loads issued ~3500 cycles earlier -> free.
// Single __syncthreads per iteration (double buffer makes the staging
// writes race-free against the other buffer's readers).

#define NTOK   8192
#define NCODES 16384
#define DDIM   512
#define NCHUNK 8
#define CHUNK  2048
#define DIST_THR 900.0f

typedef unsigned short u16;
typedef _Float16 half8 __attribute__((ext_vector_type(8)));
typedef float    f32x4 __attribute__((ext_vector_type(4)));

// ---------------- kernel 1: merged prep -------------------------------------
// blocks [0,2048): convert+swizzle x -> xh/xl
// blocks [2048,6144): convert+swizzle codes -> ch/cl
// blocks [6144,10240): c2[c] = ||codes[c]||^2 (one wave per code)
//
// Swizzle: linear index c (8 halfs each):
//   r=c&15, q=(c>>4)&3, g=(c>>6)&7, kit=(c>>9)&15, tile=c>>13
//   row = tile*128 + g*16 + r ; k = kit*32 + q*8
// Each (tile,kit) is a contiguous 8KB block in exactly the LDS fragment
// layout the GEMM wants (lane L <-> row base+(L&15), k-quad L>>4).
__device__ __forceinline__ void conv_body(const float* __restrict__ src,
                                          u16* __restrict__ dh,
                                          u16* __restrict__ dl, int c) {
    int r = c & 15, q = (c >> 4) & 3, g = (c >> 6) & 7, kit = (c >> 9) & 15;
    int tile = c >> 13;
    int row = tile * 128 + g * 16 + r;
    int k = kit * 32 + q * 8;
    const float* p = src + (size_t)row * DDIM + k;
    float4 v0 = *(const float4*)p;
    float4 v1 = *(const float4*)(p + 4);
    float vv[8] = {v0.x, v0.y, v0.z, v0.w, v1.x, v1.y, v1.z, v1.w};
    u16 hs[8], ls[8];
    #pragma unroll
    for (int j = 0; j < 8; ++j) {
        float sv = vv[j] * 16.0f;              // scale 16: keeps lo out of denorms
        _Float16 h = (_Float16)sv;
        float hf = (float)h;
        _Float16 l = (_Float16)(sv - hf);
        union { _Float16 f; u16 u; } uh, ul;
        uh.f = h; ul.f = l;
        hs[j] = uh.u; ls[j] = ul.u;
    }
    uint4 H, L;
    H.x = hs[0] | ((unsigned)hs[1] << 16); H.y = hs[2] | ((unsigned)hs[3] << 16);
    H.z = hs[4] | ((unsigned)hs[5] << 16); H.w = hs[6] | ((unsigned)hs[7] << 16);
    L.x = ls[0] | ((unsigned)ls[1] << 16); L.y = ls[2] | ((unsigned)ls[3] << 16);
    L.z = ls[4] | ((unsigned)ls[5] << 16); L.w = ls[6] | ((unsigned)ls[7] << 16);
    *(uint4*)(dh + (size_t)c * 8) = H;
    *(uint4*)(dl + (size_t)c * 8) = L;
}

__global__ __launch_bounds__(256) void nn_prep(const float* __restrict__ x,
                                               const float* __restrict__ codes,
                                               u16* __restrict__ xh, u16* __restrict__ xl,
                                               u16* __restrict__ ch, u16* __restrict__ cl,
                                               float* __restrict__ c2) {
    int b = blockIdx.x;
    if (b < 2048) {
        conv_body(x, xh, xl, b * 256 + threadIdx.x);
    } else if (b < 6144) {
        conv_body(codes, ch, cl, (b - 2048) * 256 + threadIdx.x);
    } else {
        int w = threadIdx.x >> 6;
        int lane = threadIdx.x & 63;
        int c = (b - 6144) * 4 + w;
        const float* p = codes + (size_t)c * DDIM + lane * 8;
        float4 v0 = *(const float4*)p;
        float4 v1 = *(const float4*)(p + 4);
        float s = v0.x*v0.x + v0.y*v0.y + v0.z*v0.z + v0.w*v0.w
                + v1.x*v1.x + v1.y*v1.y + v1.z*v1.z + v1.w*v1.w;
        #pragma unroll
        for (int off = 32; off > 0; off >>= 1) s += __shfl_down(s, off);
        if (lane == 0) c2[c] = s;
    }
}

// ---------------- kernel 2: pipelined fp16x3 MFMA GEMM + fused argmin -------
// grid = 32 mtiles * 8 chunks, blockIdx.x = mtile*8 + chunk (chunk<->XCD:
// each XCD's 32 co-resident blocks share one 4MB B-set = its L2).
// Block: 512 threads = 8 waves (wm=wave&3 row-quarter, wn=wave>>2 col-half);
// block tile 256 rows x 256 cols per nt (nt=0..7 over CHUNK=2048).
// Wave tile 64x128. LDS: 2 x 64KB ping-pong [Ah 16K|Al 16K|Bh 16K|Bl 16K].
__global__ __launch_bounds__(512, 2) void nn_gemm(const u16* __restrict__ xh,
                                                  const u16* __restrict__ xl,
                                                  const u16* __restrict__ chh,
                                                  const u16* __restrict__ cll,
                                                  const float* __restrict__ c2,
                                                  float* __restrict__ pmin,
                                                  int* __restrict__ pid) {
    __shared__ __align__(16) char smem[131072];
    const int tid = threadIdx.x;
    const int lane = tid & 63;
    const int wave = tid >> 6;          // 0..7
    const int wm = wave & 3;            // 64-row quarter
    const int wn = wave >> 2;           // 128-col half
    const int mtile = blockIdx.x >> 3;  // 0..31
    const int chunk = blockIdx.x & 7;   // 0..7
    const int m0 = mtile * 256;

    // wave-static staging role: plane = wave>>1 (0 Ah,1 Al,2 Bh,3 Bl),
    // tsub = wave&1 selects which 128-row/col subtile of the 256-tile.
    const int plane = wave >> 1;
    const int tsub  = wave & 1;
    const bool isA = (plane < 2);
    const u16* gbase;
    if (plane == 0)      gbase = xh  + ((size_t)(mtile * 2 + tsub) * 16) * 4096;
    else if (plane == 1) gbase = xl  + ((size_t)(mtile * 2 + tsub) * 16) * 4096;
    else if (plane == 2) gbase = chh + ((size_t)(chunk * 16 + tsub) * 16) * 4096;
    else                 gbase = cll + ((size_t)(chunk * 16 + tsub) * 16) * 4096;
    gbase += lane * 8;
    // LDS dst region for this wave: plane p at p*16KB, subtile at tsub*8KB
    const int ldsoff = wave * 8192;     // == plane*16384 + tsub*8192

    float mv[16];
    int   mi[16];
    #pragma unroll
    for (int s = 0; s < 16; ++s) { mv[s] = 3.4e38f; mi[s] = 0; }

    f32x4 acc[4][8];
    #pragma unroll
    for (int i = 0; i < 4; ++i)
        #pragma unroll
        for (int j = 0; j < 8; ++j) acc[i][j] = (f32x4)0.0f;

    // stage iteration it2 = nt*16 + kit into buffer (it2&1)
    auto stage = [&](int it2) {
        int kit2 = it2 & 15, nt2 = it2 >> 4;
        size_t off = (size_t)(isA ? kit2 : nt2 * 32 + kit2) * 4096;
        const u16* src = gbase + off;
        char* dst = smem + (size_t)(it2 & 1) * 65536 + ldsoff;
        #pragma unroll
        for (int s = 0; s < 8; ++s)
            __builtin_amdgcn_global_load_lds(
                (const __attribute__((address_space(1))) void*)(src + s * 512),
                (__attribute__((address_space(3))) void*)(dst + s * 1024),
                16, 0, 0);
    };

    stage(0);
    for (int it = 0; it < 128; ++it) {
        // Drains vmcnt(0): this wave's only outstanding loads are stage(it)
        // issued ~3500 cycles ago (mid previous iteration) -> drain is free.
        // Also publishes them cross-wave: buf[it&1] now fully staged.
        __syncthreads();

        const char* cur = smem + (size_t)(it & 1) * 65536;
        half8 ah[4], al[4], bh[8], bl[8];
        #pragma unroll
        for (int i = 0; i < 4; ++i) {
            int g = wm * 4 + i;                 // A group (16 rows each)
            ah[i] = *(const half8*)(cur +         g * 1024 + lane * 16);
            al[i] = *(const half8*)(cur + 16384 + g * 1024 + lane * 16);
        }
        #pragma unroll
        for (int j = 0; j < 8; ++j) {
            int g = wn * 8 + j;                 // B group (16 cols each)
            bh[j] = *(const half8*)(cur + 32768 + g * 1024 + lane * 16);
            bl[j] = *(const half8*)(cur + 49152 + g * 1024 + lane * 16);
        }

        // Pin order: ds_reads above, stage loads below. Prevents the
        // legalizer from ever seeing a ds_read after an outstanding
        // global_load_lds (which would reinsert the vmcnt drain).
        __builtin_amdgcn_sched_barrier(0);

        // Issue next iteration's staging EARLY: ~96 MFMAs of latency-hiding
        // distance before the end-of-iteration __syncthreads drains them.
        if (it < 127) stage(it + 1);

        #pragma unroll
        for (int j = 0; j < 8; ++j)
            #pragma unroll
            for (int i = 0; i < 4; ++i) {
                acc[i][j] = __builtin_amdgcn_mfma_f32_16x16x32_f16(ah[i], bh[j], acc[i][j], 0, 0, 0);
                acc[i][j] = __builtin_amdgcn_mfma_f32_16x16x32_f16(ah[i], bl[j], acc[i][j], 0, 0, 0);
                acc[i][j] = __builtin_amdgcn_mfma_f32_16x16x32_f16(al[i], bh[j], acc[i][j], 0, 0, 0);
            }

        if ((it & 15) == 15) {
            // epilogue for nt: score = ||c||^2 - acc/128 (acc = 256 * x.c).
            // candidates arrive in increasing code id -> '<' keeps first.
            int nt = it >> 4;
            #pragma unroll
            for (int j = 0; j < 8; ++j) {
                int ncol = nt * 256 + wn * 128 + j * 16 + (lane & 15);
                int gid = chunk * CHUNK + ncol;
                float cv = c2[gid];
                #pragma unroll
                for (int i = 0; i < 4; ++i)
                    #pragma unroll
                    for (int r = 0; r < 4; ++r) {
                        float s = fmaf(acc[i][j][r], -0.0078125f, cv);
                        int slot = i * 4 + r;
                        if (s < mv[slot]) { mv[slot] = s; mi[slot] = gid; }
                    }
            }
            #pragma unroll
            for (int i = 0; i < 4; ++i)
                #pragma unroll
                for (int j = 0; j < 8; ++j) acc[i][j] = (f32x4)0.0f;
        }
    }

    // shuffle pre-reduce across the 16 col-owner lanes (xor 1,2,4,8 stay
    // within the quad; lane>>4 = row quad is preserved).
    #pragma unroll
    for (int off = 1; off < 16; off <<= 1) {
        #pragma unroll
        for (int s = 0; s < 16; ++s) {
            float ov = __shfl_xor(mv[s], off);
            int   oi = __shfl_xor(mi[s], off);
            if (ov < mv[s] || (ov == mv[s] && oi < mi[s])) { mv[s] = ov; mi[s] = oi; }
        }
    }
    // 2 contributors per row (wn=0,1); 4KB scratch aliases buf0 (last buf0
    // readers finished before entering it=127's top __syncthreads).
    if ((lane & 15) == 0) {
        #pragma unroll
        for (int i = 0; i < 4; ++i)
            #pragma unroll
            for (int r = 0; r < 4; ++r) {
                int row = wm * 64 + i * 16 + (lane >> 4) * 4 + r;
                int2 e;
                e.x = __float_as_int(mv[i * 4 + r]);
                e.y = mi[i * 4 + r];
                *(int2*)(smem + (wn * 256 + row) * 8) = e;
            }
    }
    __syncthreads();
    if (tid < 256) {
        int2 e0 = *(const int2*)(smem + tid * 8);
        int2 e1 = *(const int2*)(smem + (256 + tid) * 8);
        float v0 = __int_as_float(e0.x), v1 = __int_as_float(e1.x);
        float bv = v0; int bi = e0.y;
        if (v1 < bv || (v1 == bv && e1.y < bi)) { bv = v1; bi = e1.y; }
        pmin[(size_t)(m0 + tid) * NCHUNK + chunk] = bv;
        pid [(size_t)(m0 + tid) * NCHUNK + chunk] = bi;
    }
}

// ---------------- kernel 3: finalize (one wave per token) -------------------
__global__ __launch_bounds__(256) void nn_fin(const float* __restrict__ x,
                                              const float* __restrict__ pmin,
                                              const int* __restrict__ pid,
                                              int* __restrict__ out) {
    int w = threadIdx.x >> 6;
    int lane = threadIdx.x & 63;
    int t = blockIdx.x * 4 + w;
    const float* p = x + (size_t)t * DDIM + lane * 8;
    float4 v0 = *(const float4*)p;
    float4 v1 = *(const float4*)(p + 4);
    float s = v0.x*v0.x + v0.y*v0.y + v0.z*v0.z + v0.w*v0.w
            + v1.x*v1.x + v1.y*v1.y + v1.z*v1.z + v1.w*v1.w;
    #pragma unroll
    for (int off = 32; off > 0; off >>= 1) s += __shfl_down(s, off);
    if (lane == 0) {
        const float* pm = pmin + (size_t)t * NCHUNK;
        const int*   pi = pid  + (size_t)t * NCHUNK;
        float bv = pm[0]; int bi = pi[0];
        #pragma unroll
        for (int c = 1; c < NCHUNK; ++c) {
            float v = pm[c]; int id = pi[c];
            if (v < bv || (v == bv && id < bi)) { bv = v; bi = id; }
        }
        float mind = s + bv;   // ||x||^2 + min(||c||^2 - 2 x.c)
        out[t] = (mind <= DIST_THR) ? bi : -1;
    }
}

extern "C" void kernel_launch(void* const* d_in, const int* in_sizes, int n_in,
                              void* d_out, int out_size, void* d_ws, size_t ws_size,
                              hipStream_t stream) {
    const float* x     = (const float*)d_in[0];
    const float* codes = (const float*)d_in[1];
    int* out = (int*)d_out;

    // workspace layout (bytes):
    //  xh 8MB | xl 8MB | ch 16MB | cl 16MB | c2 64KB | pmin 256KB | pid 256KB
    char* ws = (char*)d_ws;
    u16*   xh   = (u16*)(ws);
    u16*   xl   = (u16*)(ws + 8388608);
    u16*   chh  = (u16*)(ws + 16777216);
    u16*   cll  = (u16*)(ws + 33554432);
    float* c2   = (float*)(ws + 50331648);
    float* pmin = (float*)(ws + 50397184);
    int*   pid  = (int*)  (ws + 50659328);

    nn_prep<<<10240, 256, 0, stream>>>(x, codes, xh, xl, chh, cll, c2);
    nn_gemm<<<32 * NCHUNK, 512, 0, stream>>>(xh, xl, chh, cll, c2, pmin, pid);
    nn_fin<<<NTOK / 4, 256, 0, stream>>>(x, pmin, pid, out);
}